// Round 5
// baseline (160.312 us; speedup 1.0000x reference)
//
#include <hip/hip_runtime.h>

#define CROPPX 4
#define H 504
#define W 504
#define IMG 512
#define NB 16
#define NCH 3
#define KS 11
#define RAD 5
#define TW 64               // output cols per wave
#define RPS 21              // output rows per wave-segment
#define WPB 4               // waves per block
#define BROWS (RPS * WPB)   // 84 output rows per block
#define NYB 6               // 6 * 84 = 504 exactly
#define NXT 8               // ceil(504/64): last tile has 56 valid cols
#define TOTAL (RPS + 2*RAD) // 31 row ingests per wave

__global__ __launch_bounds__(256, 3) void ssim_main(const float* __restrict__ img1,
                                                    const float* __restrict__ img2,
                                                    float* __restrict__ partial) {
    const int lane = threadIdx.x & 63;
    const int wv   = threadIdx.x >> 6;
    const int gx0  = blockIdx.x * TW;                  // first output col
    const int y0   = blockIdx.y * BROWS + wv * RPS;    // first output row (this wave)
    const int b    = blockIdx.z;

    const float* p1 = img1 + (size_t)(b * NCH) * IMG * IMG + (size_t)CROPPX * IMG + CROPPX;
    const float* p2 = img2 + (size_t)(b * NCH) * IMG * IMG + (size_t)CROPPX * IMG + CROPPX;

    const int  c        = gx0 + lane;            // this lane's output col
    const bool colValid = c < W;
    const int  colBase  = c - RAD;               // first tap col (may be -5..510)
    const bool boundary = (blockIdx.x == 0) || (blockIdx.x == NXT - 1);  // wave-uniform

    // per-tap column validity multipliers (only applied in boundary tiles)
    float mk[KS];
    #pragma unroll
    for (int j = 0; j < KS; ++j)
        mk[j] = ((unsigned)(colBase + j) < (unsigned)W) ? 1.f : 0.f;

    // register-resident history ring: 11 rows x 5 stats (compile-time indices)
    float r1[KS], r2[KS], r11[KS], r22[KS], r12[KS];
    #pragma unroll
    for (int j = 0; j < KS; ++j) { r1[j]=0.f; r2[j]=0.f; r11[j]=0.f; r22[j]=0.f; r12[j]=0.f; }

    float vs1 = 0.f, vs2 = 0.f, vs11 = 0.f, vs22 = 0.f, vs12 = 0.f;
    float ssum = 0.f;
    const float C1 = 6.5025f, C2 = 58.5225f;
    const float inv121 = 1.0f / 121.0f;

    // prefetched next-row tap values (11 per image, all scalar coalesced loads)
    float na[KS], nb[KS];
    {
        const int r  = y0 - RAD;
        const int rc = min(max(r, 0), H - 1);
        const float* q1 = p1 + (size_t)rc * IMG + colBase;
        const float* q2 = p2 + (size_t)rc * IMG + colBase;
        #pragma unroll
        for (int j = 0; j < KS; ++j) { na[j] = q1[j]; nb[j] = q2[j]; }
    }

    for (int base = 0; base < TOTAL; base += KS) {   // base in {0,11,22}; base%11==0
        #pragma unroll
        for (int j = 0; j < KS; ++j) {
            const int iter = base + j;
            if (iter >= TOTAL) break;

            // consume prefetched row (register rename, no copies in final asm)
            float ca[KS], cb[KS];
            #pragma unroll
            for (int t = 0; t < KS; ++t) { ca[t] = na[t]; cb[t] = nb[t]; }

            // issue next row's 22 loads (deep MLP, hidden behind compute below)
            if (iter + 1 < TOTAL) {
                const int r  = y0 - RAD + iter + 1;
                const int rc = min(max(r, 0), H - 1);
                const float* q1 = p1 + (size_t)rc * IMG + colBase;
                const float* q2 = p2 + (size_t)rc * IMG + colBase;
                #pragma unroll
                for (int t = 0; t < KS; ++t) { na[t] = q1[t]; nb[t] = q2[t]; }
            }

            // column masking — only the two boundary tiles pay this
            if (boundary) {
                #pragma unroll
                for (int t = 0; t < KS; ++t) { ca[t] *= mk[t]; cb[t] *= mk[t]; }
            }

            // horizontal 11-tap sums, all in registers
            float h1 = 0.f, h2 = 0.f, h11 = 0.f, h22 = 0.f, h12 = 0.f;
            #pragma unroll
            for (int t = 0; t < KS; ++t) {
                h1 += ca[t];
                h2 += cb[t];
                h11 = fmaf(ca[t], ca[t], h11);
                h22 = fmaf(cb[t], cb[t], h22);
                h12 = fmaf(ca[t], cb[t], h12);
            }

            // row masking (wave-uniform condition)
            const int rcur = y0 - RAD + iter;
            if ((unsigned)rcur >= (unsigned)H) { h1 = 0.f; h2 = 0.f; h11 = 0.f; h22 = 0.f; h12 = 0.f; }

            // vertical sliding window; ring slot == iter % 11 == j
            vs1  += h1  - r1[j];  r1[j]  = h1;
            vs2  += h2  - r2[j];  r2[j]  = h2;
            vs11 += h11 - r11[j]; r11[j] = h11;
            vs22 += h22 - r22[j]; r22[j] = h22;
            vs12 += h12 - r12[j]; r12[j] = h12;

            // window covers rows [iter-10, iter] => output row iter-5 of segment
            if (iter >= 2 * RAD && colValid) {
                const float mu1 = vs1 * inv121;
                const float mu2 = vs2 * inv121;
                const float mu1s = mu1 * mu1;
                const float mu2s = mu2 * mu2;
                const float m12  = mu1 * mu2;
                const float s1  = fmaf(vs11, inv121, -mu1s);
                const float s2  = fmaf(vs22, inv121, -mu2s);
                const float s12 = fmaf(vs12, inv121, -m12);
                const float num = (2.0f * m12 + C1) * (2.0f * s12 + C2);
                const float den = (mu1s + mu2s + C1) * (s1 + s2 + C2);
                ssum = fmaf(num, __builtin_amdgcn_rcpf(den), ssum);
            }
        }
    }

    // wave (64-lane) reduction of ssum
    for (int off = 32; off > 0; off >>= 1)
        ssum += __shfl_down(ssum, off);
    if (lane == 0) {
        const int bidx = (((blockIdx.z * gridDim.y + blockIdx.y) * gridDim.x + blockIdx.x) * WPB) + wv;
        partial[bidx] = ssum;
    }
}

__global__ __launch_bounds__(256) void ssim_final(const float* __restrict__ partial,
                                                  int n, float* __restrict__ out) {
    __shared__ double sh[256];
    double s = 0.0;
    for (int i = threadIdx.x; i < n; i += 256) s += (double)partial[i];
    sh[threadIdx.x] = s;
    __syncthreads();
    for (int stride = 128; stride > 0; stride >>= 1) {
        if (threadIdx.x < stride) sh[threadIdx.x] += sh[threadIdx.x + stride];
        __syncthreads();
    }
    if (threadIdx.x == 0)
        out[0] = (float)(sh[0] / ((double)NB * (double)H * (double)W));
}

extern "C" void kernel_launch(void* const* d_in, const int* in_sizes, int n_in,
                              void* d_out, int out_size, void* d_ws, size_t ws_size,
                              hipStream_t stream) {
    const float* img1 = (const float*)d_in[0];
    const float* img2 = (const float*)d_in[1];
    float* out = (float*)d_out;
    float* partial = (float*)d_ws;  // NXT*NYB*NB*WPB floats = 12 KiB

    dim3 grid(NXT, NYB, NB);
    ssim_main<<<grid, 256, 0, stream>>>(img1, img2, partial);
    ssim_final<<<1, 256, 0, stream>>>(partial, NXT * NYB * NB * WPB, out);
}

// Round 7
// 135.551 us; speedup vs baseline: 1.1827x; 1.1827x over previous
//
#include <hip/hip_runtime.h>

#define CROPPX 4
#define H 504
#define W 504
#define IMG 512
#define NB 16
#define NCH 3
#define KS 11
#define RAD 5
#define TW 64               // output cols per block (one wave)
#define STRIP (TW + 2*RAD)  // 74 input cols per block
#define RPS 21              // output rows per segment (24*21 = 504 exactly)
#define NSEG 24
#define NXT 8               // ceil(504/64): last tile has 56 valid cols
#define TOTAL (RPS + 2*RAD) // 31 row ingests per block

__global__ __launch_bounds__(64) void ssim_main(const float* __restrict__ img1,
                                                const float* __restrict__ img2,
                                                float* __restrict__ partial) {
    const int tid = threadIdx.x;
    const int gx0 = blockIdx.x * TW;
    const int y0  = blockIdx.y * RPS;
    const int b   = blockIdx.z;

    // 11 rotating row buffers; body `iter` uses buf[iter%11]. Correctness needs
    // an explicit compiler fence between publish and read: per-thread alias
    // analysis cannot see cross-lane LDS deps, and WILL hoist neighbor reads
    // above the write (R6 failure). wave_barrier = 0-instruction fence; the DS
    // pipe is in-order per wave, so no s_barrier / waitcnt drain is needed.
    __shared__ float2 buf[KS][STRIP];   // 11 x 74 x 8B = 6.5 KB

    const float* p1 = img1 + (size_t)(b * NCH) * IMG * IMG + (size_t)CROPPX * IMG + CROPPX;
    const float* p2 = img2 + (size_t)(b * NCH) * IMG * IMG + (size_t)CROPPX * IMG + CROPPX;

    const int  c0   = gx0 - RAD + tid;          // strip col (first 64)
    const int  c0c  = min(max(c0, 0), W - 1);
    const bool c0ok = (unsigned)c0 < (unsigned)W;
    const int  c1   = c0 + 64;                  // strip col (10 lanes)
    const int  c1c  = min(c1, W - 1);
    const bool c1ok = (unsigned)c1 < (unsigned)W;
    const bool lane2 = tid < (STRIP - 64);

    // register history ring: 11 rows x 5 stats, compile-time indices via full unroll
    float r1[KS], r2[KS], r11[KS], r22[KS], r12[KS];
    #pragma unroll
    for (int j = 0; j < KS; ++j) { r1[j]=0.f; r2[j]=0.f; r11[j]=0.f; r22[j]=0.f; r12[j]=0.f; }

    float vs1 = 0.f, vs2 = 0.f, vs11 = 0.f, vs22 = 0.f, vs12 = 0.f;
    float ssum = 0.f;
    const float C1 = 6.5025f, C2 = 58.5225f;
    const float inv121 = 1.0f / 121.0f;
    const bool colValid = (gx0 + tid) < W;

    // two staging register sets (prefetch depth 2), parity-indexed (compile-time)
    float sa0[2], sb0[2], sa1[2], sb1[2];

    #define LOAD_ROW(slot, rowIdx)                                            \
    {                                                                         \
        const int r_  = (rowIdx);                                             \
        const int rc_ = min(max(r_, 0), H - 1);                               \
        const bool rok_ = (unsigned)r_ < (unsigned)H;                         \
        const size_t ro_ = (size_t)rc_ * IMG;                                 \
        const float ta0_ = p1[ro_ + c0c], tb0_ = p2[ro_ + c0c];               \
        sa0[slot] = (rok_ && c0ok) ? ta0_ : 0.f;                              \
        sb0[slot] = (rok_ && c0ok) ? tb0_ : 0.f;                              \
        float ta1_ = 0.f, tb1_ = 0.f;                                         \
        if (lane2) { ta1_ = p1[ro_ + c1c]; tb1_ = p2[ro_ + c1c]; }            \
        sa1[slot] = (rok_ && c1ok) ? ta1_ : 0.f;                              \
        sb1[slot] = (rok_ && c1ok) ? tb1_ : 0.f;                              \
    }

    LOAD_ROW(0, y0 - RAD)      // row for iter 0
    LOAD_ROW(1, y0 - RAD + 1)  // row for iter 1

    #pragma unroll
    for (int iter = 0; iter < TOTAL; ++iter) {
        const int slot = iter % KS;    // LDS buffer + ring slot (compile-time)
        const int par  = iter & 1;     // staging set (compile-time)

        // publish staged row `iter` to its rotating buffer
        buf[slot][tid] = make_float2(sa0[par], sb0[par]);
        if (lane2) buf[slot][64 + tid] = make_float2(sa1[par], sb1[par]);

        // refill this staging set with row iter+2 (loads stay in flight across
        // the fence below — no vmcnt drain, unlike __syncthreads)
        if (iter + 2 < TOTAL) LOAD_ROW(par, y0 - RAD + iter + 2)

        // ORDERING FENCE: forbid the compiler from hoisting the cross-lane
        // ds_reads below above the ds_write publish (R6 bug). Emits no code.
        __builtin_amdgcn_wave_barrier();

        // horizontal 11-tap sums for output col gx0+tid
        float h1 = 0.f, h2 = 0.f, h11 = 0.f, h22 = 0.f, h12 = 0.f;
        #pragma unroll
        for (int dx = 0; dx < KS; ++dx) {
            const float2 ab = buf[slot][tid + dx];
            h1 += ab.x;
            h2 += ab.y;
            h11 = fmaf(ab.x, ab.x, h11);
            h22 = fmaf(ab.y, ab.y, h22);
            h12 = fmaf(ab.x, ab.y, h12);
        }

        // vertical sliding window; ring slot == iter % 11
        vs1  += h1  - r1[slot];  r1[slot]  = h1;
        vs2  += h2  - r2[slot];  r2[slot]  = h2;
        vs11 += h11 - r11[slot]; r11[slot] = h11;
        vs22 += h22 - r22[slot]; r22[slot] = h22;
        vs12 += h12 - r12[slot]; r12[slot] = h12;

        // window covers rows [iter-10, iter] => output row iter-5 of segment
        if (iter >= 2 * RAD && colValid) {
            const float mu1 = vs1 * inv121;
            const float mu2 = vs2 * inv121;
            const float mu1s = mu1 * mu1;
            const float mu2s = mu2 * mu2;
            const float m12  = mu1 * mu2;
            const float s1  = fmaf(vs11, inv121, -mu1s);
            const float s2  = fmaf(vs22, inv121, -mu2s);
            const float s12 = fmaf(vs12, inv121, -m12);
            const float num = (2.0f * m12 + C1) * (2.0f * s12 + C2);
            const float den = (mu1s + mu2s + C1) * (s1 + s2 + C2);
            ssum = fmaf(num, __builtin_amdgcn_rcpf(den), ssum);
        }
    }
    #undef LOAD_ROW

    // wave (64-lane) reduction of ssum
    for (int off = 32; off > 0; off >>= 1)
        ssum += __shfl_down(ssum, off);
    if (tid == 0) {
        const int bidx = (blockIdx.z * gridDim.y + blockIdx.y) * gridDim.x + blockIdx.x;
        partial[bidx] = ssum;
    }
}

__global__ __launch_bounds__(256) void ssim_final(const float* __restrict__ partial,
                                                  int n, float* __restrict__ out) {
    __shared__ double sh[256];
    double s = 0.0;
    for (int i = threadIdx.x; i < n; i += 256) s += (double)partial[i];
    sh[threadIdx.x] = s;
    __syncthreads();
    for (int stride = 128; stride > 0; stride >>= 1) {
        if (threadIdx.x < stride) sh[threadIdx.x] += sh[threadIdx.x + stride];
        __syncthreads();
    }
    if (threadIdx.x == 0)
        out[0] = (float)(sh[0] / ((double)NB * (double)H * (double)W));
}

extern "C" void kernel_launch(void* const* d_in, const int* in_sizes, int n_in,
                              void* d_out, int out_size, void* d_ws, size_t ws_size,
                              hipStream_t stream) {
    const float* img1 = (const float*)d_in[0];
    const float* img2 = (const float*)d_in[1];
    float* out = (float*)d_out;
    float* partial = (float*)d_ws;  // NXT*NSEG*NB floats = 12 KiB

    dim3 grid(NXT, NSEG, NB);
    ssim_main<<<grid, 64, 0, stream>>>(img1, img2, partial);
    ssim_final<<<1, 256, 0, stream>>>(partial, NXT * NSEG * NB, out);
}